// Round 2
// baseline (43.733 us; speedup 1.0000x reference)
//
#include <hip/hip_runtime.h>

// DiceLoss: input (B=16, C=4, H=512, W=512) f32, target (B,H,W) int32.
// pred = argmax_c input; per class c: pp=#pred==c, tt=#tgt==c, ii=#(pred==c & tgt==c).
// loss = mean_c (1 - (2*ii+eps)/(pp+tt+eps)).

static constexpr int kHW    = 512 * 512;       // 262144
static constexpr int kB     = 16;
static constexpr int kC     = 4;
static constexpr int kNPix  = kB * kHW;        // 4194304
static constexpr int kNVec  = kNPix / 4;       // 1048576 quads
static constexpr int kBlocks  = 2048;
static constexpr int kThreads = 256;
static constexpr int kT       = kBlocks * kThreads;  // 524288 threads
static constexpr int kIters   = kNVec / kT;          // 2 quads/thread (exact)
static constexpr float kEps = 1e-6f;

// partials layout: partial[c * kBlocks + blk], c in [0,12)
__global__ __launch_bounds__(kThreads) void dice_count_kernel(
    const float* __restrict__ in, const int* __restrict__ tgt,
    unsigned int* __restrict__ partial)
{
    const int tid = blockIdx.x * kThreads + threadIdx.x;

    // byte-packed per-class counters; max 8 pixels/thread -> fields <= 8
    unsigned int pp = 0, tt = 0, ii = 0;

#pragma unroll
    for (int it = 0; it < kIters; ++it) {
        const int v  = tid + it * kT;
        const int p  = v << 2;           // first pixel of quad
        const int b  = p >> 18;          // p / kHW
        const int hw = p & (kHW - 1);    // p % kHW
        const float* base = in + (size_t)b * (kC * kHW) + hw;
        const float4 c0 = *(const float4*)(base);
        const float4 c1 = *(const float4*)(base + kHW);
        const float4 c2 = *(const float4*)(base + 2 * kHW);
        const float4 c3 = *(const float4*)(base + 3 * kHW);
        const int4   t4 = *(const int4*)(tgt + p);

        const float a0[4] = {c0.x, c0.y, c0.z, c0.w};
        const float a1[4] = {c1.x, c1.y, c1.z, c1.w};
        const float a2[4] = {c2.x, c2.y, c2.z, c2.w};
        const float a3[4] = {c3.x, c3.y, c3.z, c3.w};
        const int   tv[4] = {t4.x, t4.y, t4.z, t4.w};

#pragma unroll
        for (int j = 0; j < 4; ++j) {
            // argmax, first-occurrence tie-break (strict >)
            int pred = 0; float bv = a0[j];
            if (a1[j] > bv) { bv = a1[j]; pred = 1; }
            if (a2[j] > bv) { bv = a2[j]; pred = 2; }
            if (a3[j] > bv) { bv = a3[j]; pred = 3; }
            const int t = tv[j];
            pp += 1u << (pred << 3);
            tt += 1u << (t << 3);
            ii += (unsigned int)(pred == t) << (t << 3);
        }
    }

    // packed butterfly over 16 lanes (max field value 8*16=128 < 256, no overflow)
#pragma unroll
    for (int o = 1; o <= 8; o <<= 1) {
        pp += __shfl_xor(pp, o, 64);
        tt += __shfl_xor(tt, o, 64);
        ii += __shfl_xor(ii, o, 64);
    }

    // unpack to 12 counters, finish wave reduction (lanes 16, 32 apart)
    unsigned int loc[12];
#pragma unroll
    for (int c = 0; c < 4; ++c) {
        loc[c]     = (pp >> (c * 8)) & 0xFF;
        loc[4 + c] = (tt >> (c * 8)) & 0xFF;
        loc[8 + c] = (ii >> (c * 8)) & 0xFF;
    }
#pragma unroll
    for (int i = 0; i < 12; ++i) {
        loc[i] += __shfl_xor(loc[i], 16, 64);
        loc[i] += __shfl_xor(loc[i], 32, 64);
    }

    // block reduction across 4 waves
    __shared__ unsigned int s[4][12];
    const int wave = threadIdx.x >> 6;
    if ((threadIdx.x & 63) == 0) {
#pragma unroll
        for (int i = 0; i < 12; ++i) s[wave][i] = loc[i];
    }
    __syncthreads();
    if (threadIdx.x < 12) {
        const unsigned int sum = s[0][threadIdx.x] + s[1][threadIdx.x]
                               + s[2][threadIdx.x] + s[3][threadIdx.x];
        partial[threadIdx.x * kBlocks + blockIdx.x] = sum;  // non-atomic, fully overwritten
    }
}

__global__ __launch_bounds__(256) void dice_final_kernel(
    const unsigned int* __restrict__ partial, float* __restrict__ out)
{
    unsigned int loc[12];
#pragma unroll
    for (int c = 0; c < 12; ++c) {
        unsigned int x = 0;
        for (int t = threadIdx.x; t < kBlocks; t += 256)
            x += partial[c * kBlocks + t];
        loc[c] = x;
    }
#pragma unroll
    for (int i = 0; i < 12; ++i) {
#pragma unroll
        for (int o = 1; o <= 32; o <<= 1) loc[i] += __shfl_xor(loc[i], o, 64);
    }

    __shared__ unsigned int s[4][12];
    const int wave = threadIdx.x >> 6;
    if ((threadIdx.x & 63) == 0) {
#pragma unroll
        for (int i = 0; i < 12; ++i) s[wave][i] = loc[i];
    }
    __syncthreads();

    if (threadIdx.x == 0) {
        float loss = 0.0f;
#pragma unroll
        for (int c = 0; c < kC; ++c) {
            const float ppc = (float)(s[0][c] + s[1][c] + s[2][c] + s[3][c]);
            const float ttc = (float)(s[0][4+c] + s[1][4+c] + s[2][4+c] + s[3][4+c]);
            const float iic = (float)(s[0][8+c] + s[1][8+c] + s[2][8+c] + s[3][8+c]);
            const float dice = (2.0f * iic + kEps) / (ppc + ttc + kEps);
            loss += 1.0f - dice;
        }
        out[0] = loss * 0.25f;
    }
}

extern "C" void kernel_launch(void* const* d_in, const int* in_sizes, int n_in,
                              void* d_out, int out_size, void* d_ws, size_t ws_size,
                              hipStream_t stream) {
    const float* in  = (const float*)d_in[0];
    const int*   tgt = (const int*)d_in[1];
    float* out = (float*)d_out;
    unsigned int* partial = (unsigned int*)d_ws;  // 12 * kBlocks uints = 96 KiB

    dice_count_kernel<<<kBlocks, kThreads, 0, stream>>>(in, tgt, partial);
    dice_final_kernel<<<1, 256, 0, stream>>>(partial, out);
}

// Round 3
// 22.705 us; speedup vs baseline: 1.9261x; 1.9261x over previous
//
#include <hip/hip_runtime.h>

// DiceLoss: input (B=16, C=4, H=512, W=512) f32, target (B,H,W) int32.
// pred = argmax_c input; per class c: pp=#pred==c, tt=#tgt==c, ii=#(pred==c & tgt==c).
// loss = mean_c (1 - (2*ii+eps)/(pp+tt+eps)).

static constexpr int kHW     = 512 * 512;       // 262144
static constexpr int kC      = 4;
static constexpr int kNPix   = 16 * kHW;        // 4194304
static constexpr int kNVec   = kNPix / 4;       // 1048576 quads
static constexpr int kBlocks  = 1024;
static constexpr int kThreads = 256;
static constexpr int kT       = kBlocks * kThreads;  // 262144 threads
static constexpr int kQT      = kNVec / kT;          // 4 quads/thread (exact)
static constexpr float kEps = 1e-6f;

__device__ __forceinline__ void quad_count(
    const float4& c0, const float4& c1, const float4& c2, const float4& c3,
    const int4& t4, unsigned int& pp, unsigned int& tt, unsigned int& ii)
{
    const float a0[4] = {c0.x, c0.y, c0.z, c0.w};
    const float a1[4] = {c1.x, c1.y, c1.z, c1.w};
    const float a2[4] = {c2.x, c2.y, c2.z, c2.w};
    const float a3[4] = {c3.x, c3.y, c3.z, c3.w};
    const int   tv[4] = {t4.x, t4.y, t4.z, t4.w};
#pragma unroll
    for (int j = 0; j < 4; ++j) {
        int pred = 0; float bv = a0[j];
        if (a1[j] > bv) { bv = a1[j]; pred = 1; }
        if (a2[j] > bv) { bv = a2[j]; pred = 2; }
        if (a3[j] > bv) { bv = a3[j]; pred = 3; }
        const int t = tv[j];
        pp += 1u << (pred << 3);
        tt += 1u << (t << 3);
        ii += (unsigned int)(pred == t) << (t << 3);
    }
}

// partials layout: partial[c * kBlocks + blk], c in [0,12)
__global__ __launch_bounds__(kThreads) void dice_count_kernel(
    const float* __restrict__ in, const int* __restrict__ tgt,
    unsigned int* __restrict__ partial)
{
    const int tid = blockIdx.x * kThreads + threadIdx.x;

    unsigned int pp = 0, tt = 0, ii = 0;   // byte-packed; max 16 pixels/thread per field

#pragma unroll
    for (int it = 0; it < kQT; it += 2) {
        const int v0 = tid + it * kT;
        const int v1 = tid + (it + 1) * kT;
        const int p0 = v0 << 2, p1 = v1 << 2;
        const float* baseA = in + (size_t)(p0 >> 18) * (kC * kHW) + (p0 & (kHW - 1));
        const float* baseB = in + (size_t)(p1 >> 18) * (kC * kHW) + (p1 & (kHW - 1));

        // issue all 10 loads before consuming any
        const float4 A0 = *(const float4*)(baseA);
        const float4 A1 = *(const float4*)(baseA + kHW);
        const float4 A2 = *(const float4*)(baseA + 2 * kHW);
        const float4 A3 = *(const float4*)(baseA + 3 * kHW);
        const int4   TA = *(const int4*)(tgt + p0);
        const float4 B0 = *(const float4*)(baseB);
        const float4 B1 = *(const float4*)(baseB + kHW);
        const float4 B2 = *(const float4*)(baseB + 2 * kHW);
        const float4 B3 = *(const float4*)(baseB + 3 * kHW);
        const int4   TB = *(const int4*)(tgt + p1);

        quad_count(A0, A1, A2, A3, TA, pp, tt, ii);
        quad_count(B0, B1, B2, B3, TB, pp, tt, ii);
    }

    // packed butterfly over 8 lanes only (fields reach 16*8=128 < 256: no overflow)
#pragma unroll
    for (int o = 1; o <= 4; o <<= 1) {
        pp += __shfl_xor(pp, o, 64);
        tt += __shfl_xor(tt, o, 64);
        ii += __shfl_xor(ii, o, 64);
    }

    // unpack, finish wave reduction at offsets 8/16/32
    unsigned int loc[12];
#pragma unroll
    for (int c = 0; c < 4; ++c) {
        loc[c]     = (pp >> (c * 8)) & 0xFF;
        loc[4 + c] = (tt >> (c * 8)) & 0xFF;
        loc[8 + c] = (ii >> (c * 8)) & 0xFF;
    }
#pragma unroll
    for (int i = 0; i < 12; ++i) {
        loc[i] += __shfl_xor(loc[i], 8, 64);
        loc[i] += __shfl_xor(loc[i], 16, 64);
        loc[i] += __shfl_xor(loc[i], 32, 64);
    }

    // block reduction across 4 waves
    __shared__ unsigned int s[4][12];
    const int wave = threadIdx.x >> 6;
    if ((threadIdx.x & 63) == 0) {
#pragma unroll
        for (int i = 0; i < 12; ++i) s[wave][i] = loc[i];
    }
    __syncthreads();
    if (threadIdx.x < 12) {
        partial[threadIdx.x * kBlocks + blockIdx.x] =
            s[0][threadIdx.x] + s[1][threadIdx.x] + s[2][threadIdx.x] + s[3][threadIdx.x];
    }
}

__global__ __launch_bounds__(256) void dice_final_kernel(
    const unsigned int* __restrict__ partial, float* __restrict__ out)
{
    const int t = threadIdx.x;
    unsigned int loc[12];
#pragma unroll
    for (int i = 0; i < 12; ++i) loc[i] = 0;

    // k outer / c inner: all 48 loads independent -> deep MLP, coalesced
#pragma unroll
    for (int k = 0; k < kBlocks / 256; ++k) {
#pragma unroll
        for (int c = 0; c < 12; ++c)
            loc[c] += partial[c * kBlocks + k * 256 + t];
    }

#pragma unroll
    for (int i = 0; i < 12; ++i) {
#pragma unroll
        for (int o = 1; o <= 32; o <<= 1) loc[i] += __shfl_xor(loc[i], o, 64);
    }

    __shared__ unsigned int s[4][12];
    const int wave = t >> 6;
    if ((t & 63) == 0) {
#pragma unroll
        for (int i = 0; i < 12; ++i) s[wave][i] = loc[i];
    }
    __syncthreads();

    if (t == 0) {
        float loss = 0.0f;
#pragma unroll
        for (int c = 0; c < kC; ++c) {
            const float ppc = (float)(s[0][c] + s[1][c] + s[2][c] + s[3][c]);
            const float ttc = (float)(s[0][4+c] + s[1][4+c] + s[2][4+c] + s[3][4+c]);
            const float iic = (float)(s[0][8+c] + s[1][8+c] + s[2][8+c] + s[3][8+c]);
            loss += 1.0f - (2.0f * iic + kEps) / (ppc + ttc + kEps);
        }
        out[0] = loss * 0.25f;
    }
}

extern "C" void kernel_launch(void* const* d_in, const int* in_sizes, int n_in,
                              void* d_out, int out_size, void* d_ws, size_t ws_size,
                              hipStream_t stream) {
    const float* in  = (const float*)d_in[0];
    const int*   tgt = (const int*)d_in[1];
    float* out = (float*)d_out;
    unsigned int* partial = (unsigned int*)d_ws;  // 12 * kBlocks uints = 48 KiB

    dice_count_kernel<<<kBlocks, kThreads, 0, stream>>>(in, tgt, partial);
    dice_final_kernel<<<1, 256, 0, stream>>>(partial, out);
}